// Round 2
// baseline (14437.244 us; speedup 1.0000x reference)
//
#include <hip/hip_runtime.h>
#include <hip/hip_bf16.h>

typedef __attribute__((ext_vector_type(8))) short bf16x8;
typedef __attribute__((ext_vector_type(4))) float f32x4;

#define MFMA16(a,b,c) __builtin_amdgcn_mfma_f32_16x16x32_bf16((a),(b),(c),0,0,0)

// ---------------- workspace layout (byte offsets), total 48 MiB ----------------
static constexpr long OFF_WT  = 0;          // bf16 transposed weights, 46,137,344 B
static constexpr long OFF_HF  = 46137344;   // h fp32 [2 parity][4 unit][64*1024] = 2,097,152 B
static constexpr long OFF_H16 = 48234496;   // h bf16 [2][4][65536] = 1,048,576 B
static constexpr long OFF_Y0R = 49283072;   // y0 ring bf16 [2 slot][2 dir][65536] = 524,288 B
static constexpr long OFF_Y1R = 49807360;   // y1 ring bf16 [2 slot][2 dir][65536] = 524,288 B
// end = 50,331,648 B (48 MiB)

// element offsets (bf16) within weight region
static constexpr long E_FW_WXT0 = 0;        // [3072][512]
static constexpr long E_FW_WHT0 = 1572864;  // [3072][1024]
static constexpr long E_FW_WXT1 = 4718592;  // [3072][1024]
static constexpr long E_FW_WHT1 = 7864320;
static constexpr long E_BW_WXT0 = 11010048;
static constexpr long E_BW_WHT0 = 12582912;
static constexpr long E_BW_WXT1 = 15728640;
static constexpr long E_BW_WHT1 = 18874368;
static constexpr long E_FCWT    = 22020096; // [512][2048]

static constexpr long OUT_FWH = 16777216;   // fw_h [2][64][1024] in d_out
static constexpr long OUT_BWH = 16908288;   // bw_h [2][64][1024]

__device__ __forceinline__ float sig_(float x) {
  x = fminf(fmaxf(x, -30.f), 30.f);
  return 1.f / (1.f + __expf(-x));
}
__device__ __forceinline__ float tanh_(float x) {
  x = fminf(fmaxf(x, -15.f), 15.f);
  float e = __expf(2.f * x);
  return (e - 1.f) / (e + 1.f);
}
__device__ __forceinline__ bf16x8 bc8(uint4 v) { return __builtin_bit_cast(bf16x8, v); }
__device__ __forceinline__ unsigned short f2bfu(float f) {
  __hip_bfloat16 h = __float2bfloat16(f);
  return *(unsigned short*)&h;
}
// load 8 contiguous fp32, convert to 8 packed bf16 (one uint4)
__device__ __forceinline__ uint4 cvt8(const float* p) {
  const float4 a = ((const float4*)p)[0];
  const float4 b = ((const float4*)p)[1];
  uint4 r;
  r.x = (unsigned)f2bfu(a.x) | ((unsigned)f2bfu(a.y) << 16);
  r.y = (unsigned)f2bfu(a.z) | ((unsigned)f2bfu(a.w) << 16);
  r.z = (unsigned)f2bfu(b.x) | ((unsigned)f2bfu(b.y) << 16);
  r.w = (unsigned)f2bfu(b.z) | ((unsigned)f2bfu(b.w) << 16);
  return r;
}

// ---------------- transpose+cast: src f32 [R][C] -> dst bf16 [C][R] ----------------
__global__ void transpose_cast(const float* __restrict__ src, __hip_bfloat16* __restrict__ dst,
                               int R, int C) {
  __shared__ float tile[32][33];
  int tx = threadIdx.x, ty = threadIdx.y;
  int c0 = blockIdx.x * 32, r0 = blockIdx.y * 32;
#pragma unroll
  for (int i = 0; i < 32; i += 8) tile[ty + i][tx] = src[(long)(r0 + ty + i) * C + c0 + tx];
  __syncthreads();
#pragma unroll
  for (int i = 0; i < 32; i += 8)
    dst[(long)(c0 + ty + i) * R + r0 + tx] = __float2bfloat16(tile[tx][ty + i]);
}

// ---------------- fused step: 4 GRU units + 2 FC units, one global step s ----------------
// blocks 0..63:    unit 0  fw L0 (t=s)
// blocks 64..127:  unit 1  bw L0 (t=511-s)
// blocks 128..191: unit 2  fw L1 (t=s-1)
// blocks 192..255: unit 3  bw L1 (t=512-s)
// blocks 256..287: FC fw   (t=s-2)
// blocks 288..319: FC bw   (t=513-s)
__global__ __launch_bounds__(256)
void gru_step(const char* __restrict__ ws, int s, const float* __restrict__ xf,
              const float* __restrict__ fwbx0, const float* __restrict__ fwbh0,
              const float* __restrict__ fwbx1, const float* __restrict__ fwbh1,
              const float* __restrict__ bwbx0, const float* __restrict__ bwbh0,
              const float* __restrict__ bwbx1, const float* __restrict__ bwbh1,
              const float* __restrict__ fcb, float* __restrict__ dout) {
  __shared__ uint4 Al[64 * 17];
  __shared__ uint4 Bl[48 * 17];

  const __hip_bfloat16* wt = (const __hip_bfloat16*)(ws + OFF_WT);
  float* hF = (float*)(ws + OFF_HF);
  __hip_bfloat16* h16 = (__hip_bfloat16*)(ws + OFF_H16);
  __hip_bfloat16* y0r = (__hip_bfloat16*)(ws + OFF_Y0R);
  __hip_bfloat16* y1r = (__hip_bfloat16*)(ws + OFF_Y1R);

  const int tid = threadIdx.x;
  const int lane = tid & 63, wid = tid >> 6;
  const int rr = lane & 15, qq = lane >> 4;
  const int blk = blockIdx.x;

  if (blk >= 256) {
    // ================= FC path =================
    if (s < 2) return;
    const int sub = blk - 256;
    const int dir = sub >> 5;
    const int j0 = (sub & 31) << 4;
    const int t = dir ? (513 - s) : (s - 2);  // 0..511 for s in [2,513]
    const __hip_bfloat16* A = y1r + ((t & 1) * 2 + dir) * 65536;  // [64][1024]
    const __hip_bfloat16* B = wt + E_FCWT + dir * 1024;           // rows ld 2048

    f32x4 acc = {0.f, 0.f, 0.f, 0.f};
    uint4 pa[4], pb;
    auto ld = [&](int ch) {
      const int k0 = ch << 7;
#pragma unroll
      for (int i = 0; i < 4; i++) {
        int c = tid + (i << 8); int row = c >> 4, kc = c & 15;
        pa[i] = *(const uint4*)(A + row * 1024 + k0 + (kc << 3));
      }
      { int row = tid >> 4, kc = tid & 15;
        pb = *(const uint4*)(B + (long)(j0 + row) * 2048 + k0 + (kc << 3)); }
    };
    ld(0);
    for (int ch = 0; ch < 8; ++ch) {
      __syncthreads();
#pragma unroll
      for (int i = 0; i < 4; i++) { int c = tid + (i << 8); Al[(c >> 4) * 17 + (c & 15)] = pa[i]; }
      Bl[(tid >> 4) * 17 + (tid & 15)] = pb;
      __syncthreads();
      if (ch + 1 < 8) ld(ch + 1);
#pragma unroll
      for (int ks = 0; ks < 4; ++ks) {
        bf16x8 a = bc8(Al[(wid * 16 + rr) * 17 + ks * 4 + qq]);
        bf16x8 b = bc8(Bl[rr * 17 + ks * 4 + qq]);
        acc = MFMA16(a, b, acc);
      }
    }
    const int j = j0 + rr;
    const float bv = fcb[j];
    const bool first = dir ? (t >= 256) : (t <= 255);  // fw lands first for t<=255, bw for t>=256
#pragma unroll
    for (int g = 0; g < 4; ++g) {
      const int b = wid * 16 + qq * 4 + g;
      float* po = dout + (long)b * 262144 + (long)t * 512 + j;
      if (first) *po = acc[g] + bv;
      else       *po += acc[g];
    }
    return;
  }

  // ================= GRU path =================
  const int unit = blk >> 6;
  const int j0 = (blk & 63) << 4;

  int rp, t;
  if (unit < 2) { if (s >= 512) return; rp = s & 1; t = (unit == 0) ? s : 511 - s; }
  else          { if (s < 1 || s > 512) return; rp = (s - 1) & 1; t = (unit == 2) ? s - 1 : 512 - s; }
  const int wp = rp ^ 1;

  const __hip_bfloat16 *B1, *B2; int ldb2, K2;
  const float *bx, *bh;
  const void* A2; bool a2f; long lda2;
  int lastS; long dhOff;
  switch (unit) {
    case 0: B1 = wt + E_FW_WHT0; B2 = wt + E_FW_WXT0; ldb2 = 512; K2 = 512;
            A2 = xf + (long)t * 512; a2f = true; lda2 = 262144;
            bx = fwbx0; bh = fwbh0; lastS = 511; dhOff = OUT_FWH; break;
    case 1: B1 = wt + E_BW_WHT0; B2 = wt + E_BW_WXT0; ldb2 = 512; K2 = 512;
            A2 = xf + (long)t * 512; a2f = true; lda2 = 262144;
            bx = bwbx0; bh = bwbh0; lastS = 511; dhOff = OUT_BWH; break;
    case 2: B1 = wt + E_FW_WHT1; B2 = wt + E_FW_WXT1; ldb2 = 1024; K2 = 1024;
            A2 = y0r + ((t & 1) * 2 + 0) * 65536; a2f = false; lda2 = 1024;
            bx = fwbx1; bh = fwbh1; lastS = 512; dhOff = OUT_FWH + 65536; break;
    case 3: B1 = wt + E_BW_WHT1; B2 = wt + E_BW_WXT1; ldb2 = 1024; K2 = 1024;
            A2 = y0r + ((t & 1) * 2 + 1) * 65536; a2f = false; lda2 = 1024;
            bx = bwbx1; bh = bwbh1; lastS = 512; dhOff = OUT_BWH + 65536; break;
    default: return;
  }
  const __hip_bfloat16* A1 = h16 + (long)rp * 262144 + unit * 65536;
  const float* hOld = hF + (long)rp * 262144 + unit * 65536;
  float* hNewF = hF + (long)wp * 262144 + unit * 65536;
  __hip_bfloat16* hNew16 = h16 + (long)wp * 262144 + unit * 65536;
  __hip_bfloat16* ringOut = (unit < 2 ? y0r : y1r) + ((t & 1) * 2 + (unit & 1)) * 65536;

  const int nch = (1024 + K2) >> 7;

  uint4 pa[4], pb[3];
  auto loadchunk = [&](int ch) {
    const int k0 = ch << 7;
    if (k0 < 1024) {
#pragma unroll
      for (int i = 0; i < 4; i++) {
        int c = tid + (i << 8); int row = c >> 4, kc = c & 15;
        pa[i] = *(const uint4*)(A1 + (long)row * 1024 + k0 + (kc << 3));
      }
    } else if (!a2f) {
      const __hip_bfloat16* Ab = (const __hip_bfloat16*)A2;
#pragma unroll
      for (int i = 0; i < 4; i++) {
        int c = tid + (i << 8); int row = c >> 4, kc = c & 15;
        pa[i] = *(const uint4*)(Ab + (long)row * lda2 + (k0 - 1024) + (kc << 3));
      }
    } else {
      const float* Af = (const float*)A2;
#pragma unroll
      for (int i = 0; i < 4; i++) {
        int c = tid + (i << 8); int row = c >> 4, kc = c & 15;
        pa[i] = cvt8(Af + (long)row * lda2 + (k0 - 1024) + (kc << 3));
      }
    }
    const __hip_bfloat16* Bb; int ld, ko;
    if (k0 < 1024) { Bb = B1; ld = 1024; ko = k0; }
    else           { Bb = B2; ld = ldb2; ko = k0 - 1024; }
#pragma unroll
    for (int i = 0; i < 3; i++) {
      int c = tid + (i << 8); int row = c >> 4, kc = c & 15;
      int n = ((row >> 4) << 10) + j0 + (row & 15);
      pb[i] = *(const uint4*)(Bb + (long)n * ld + ko + (kc << 3));
    }
  };

  f32x4 aR = {0.f, 0.f, 0.f, 0.f}, aZ = {0.f, 0.f, 0.f, 0.f};
  f32x4 aNH = {0.f, 0.f, 0.f, 0.f}, aNX = {0.f, 0.f, 0.f, 0.f};

  loadchunk(0);
  for (int ch = 0; ch < nch; ++ch) {
    const bool seg1 = (ch << 7) < 1024;
    __syncthreads();
#pragma unroll
    for (int i = 0; i < 4; i++) { int c = tid + (i << 8); Al[(c >> 4) * 17 + (c & 15)] = pa[i]; }
#pragma unroll
    for (int i = 0; i < 3; i++) { int c = tid + (i << 8); Bl[(c >> 4) * 17 + (c & 15)] = pb[i]; }
    __syncthreads();
    if (ch + 1 < nch) loadchunk(ch + 1);
#pragma unroll
    for (int ks = 0; ks < 4; ++ks) {
      bf16x8 a  = bc8(Al[(wid * 16 + rr) * 17 + ks * 4 + qq]);
      bf16x8 bR = bc8(Bl[(rr)      * 17 + ks * 4 + qq]);
      bf16x8 bZ = bc8(Bl[(16 + rr) * 17 + ks * 4 + qq]);
      bf16x8 bN = bc8(Bl[(32 + rr) * 17 + ks * 4 + qq]);
      aR = MFMA16(a, bR, aR);
      aZ = MFMA16(a, bZ, aZ);
      if (seg1) aNH = MFMA16(a, bN, aNH);
      else      aNX = MFMA16(a, bN, aNX);
    }
  }

  // epilogue: gates + state update
  const int j = j0 + rr;
  const float bxr = bx[j], bxz = bx[1024 + j], bxn = bx[2048 + j];
  const float bhr = bh[j], bhz = bh[1024 + j], bhn = bh[2048 + j];
#pragma unroll
  for (int g = 0; g < 4; ++g) {
    const int b = wid * 16 + qq * 4 + g;
    const float r_ = sig_(aR[g] + bxr + bhr);
    const float z_ = sig_(aZ[g] + bxz + bhz);
    const float n_ = tanh_(aNX[g] + bxn + r_ * (aNH[g] + bhn));
    const float hv = hOld[b * 1024 + j];
    const float hn2 = (1.f - z_) * n_ + z_ * hv;
    hNewF[b * 1024 + j] = hn2;
    hNew16[b * 1024 + j] = __float2bfloat16(hn2);
    ringOut[b * 1024 + j] = __float2bfloat16(hn2);
    if (s == lastS) dout[dhOff + b * 1024 + j] = hn2;
  }
}

extern "C" void kernel_launch(void* const* d_in, const int* in_sizes, int n_in,
                              void* d_out, int out_size, void* d_ws, size_t ws_size,
                              hipStream_t stream) {
  (void)in_sizes; (void)n_in; (void)out_size; (void)ws_size;
  char* ws = (char*)d_ws;
  const float* x = (const float*)d_in[0];
  __hip_bfloat16* wt = (__hip_bfloat16*)(ws + OFF_WT);

  // zero h state (fp32 + bf16 regions are contiguous)
  hipMemsetAsync(ws + OFF_HF, 0, 3145728, stream);

  // transpose-cast weights: src [K][3072] -> dst [3072][K] (and fc [2048][512] -> [512][2048])
  dim3 tb(32, 8);
  transpose_cast<<<dim3(96, 16), tb, 0, stream>>>((const float*)d_in[1],  wt + E_FW_WXT0, 512,  3072);
  transpose_cast<<<dim3(96, 32), tb, 0, stream>>>((const float*)d_in[2],  wt + E_FW_WHT0, 1024, 3072);
  transpose_cast<<<dim3(96, 32), tb, 0, stream>>>((const float*)d_in[5],  wt + E_FW_WXT1, 1024, 3072);
  transpose_cast<<<dim3(96, 32), tb, 0, stream>>>((const float*)d_in[6],  wt + E_FW_WHT1, 1024, 3072);
  transpose_cast<<<dim3(96, 16), tb, 0, stream>>>((const float*)d_in[9],  wt + E_BW_WXT0, 512,  3072);
  transpose_cast<<<dim3(96, 32), tb, 0, stream>>>((const float*)d_in[10], wt + E_BW_WHT0, 1024, 3072);
  transpose_cast<<<dim3(96, 32), tb, 0, stream>>>((const float*)d_in[13], wt + E_BW_WXT1, 1024, 3072);
  transpose_cast<<<dim3(96, 32), tb, 0, stream>>>((const float*)d_in[14], wt + E_BW_WHT1, 1024, 3072);
  transpose_cast<<<dim3(16, 64), tb, 0, stream>>>((const float*)d_in[17], wt + E_FCWT,    2048, 512);

  const float* fwbx0 = (const float*)d_in[3];
  const float* fwbh0 = (const float*)d_in[4];
  const float* fwbx1 = (const float*)d_in[7];
  const float* fwbh1 = (const float*)d_in[8];
  const float* bwbx0 = (const float*)d_in[11];
  const float* bwbh0 = (const float*)d_in[12];
  const float* bwbx1 = (const float*)d_in[15];
  const float* bwbh1 = (const float*)d_in[16];
  const float* fcb   = (const float*)d_in[18];

  // skewed pipeline: L0 at step s, L1 at s-1, FC at s-2; 514 launches
  for (int s = 0; s <= 513; ++s) {
    gru_step<<<320, 256, 0, stream>>>(ws, s, x, fwbx0, fwbh0, fwbx1, fwbh1,
                                      bwbx0, bwbh0, bwbx1, bwbh1, fcb, (float*)d_out);
  }
}